// Round 5
// baseline (416.165 us; speedup 1.0000x reference)
//
#include <hip/hip_runtime.h>

// ---------- types ----------
typedef __attribute__((ext_vector_type(8))) __bf16 bf16x8;
typedef __attribute__((ext_vector_type(4))) float f32x4;
typedef unsigned short u16;

__device__ __forceinline__ u16 f2bf(float f) {
    union { float f; unsigned u; } v; v.f = f;
    unsigned r = v.u + 0x7FFFu + ((v.u >> 16) & 1u);
    return (u16)(r >> 16);
}
__device__ __forceinline__ float bf2f(u16 h) {
    union { unsigned u; float f; } v; v.u = ((unsigned)h) << 16;
    return v.f;
}
// native cast: single v_cvt op (RNE)
__device__ __forceinline__ u16 f2bf_n(float f) {
    union { __bf16 b; u16 u; } t; t.b = (__bf16)f; return t.u;
}
__device__ __forceinline__ bf16x8 ld_bf16x8(const u16* p) {
    union { uint4 u; bf16x8 b; } t;
    t.u = *(const uint4*)p;
    return t.b;
}
__device__ __forceinline__ void async16(const void* g, const void* l) {
    __builtin_amdgcn_global_load_lds((const __attribute__((address_space(1))) void*)g,
                                     (__attribute__((address_space(3))) void*)l, 16, 0, 0);
}

// ---------- problem constants ----------
#define BATCH 4
#define NSEQ 2048
#define HEADS 16
#define DH 64
#define DMODEL 1024
#define MROWS 8192   // B*N
#define NQKV 3072

// ---------- elementwise ----------
__global__ void split_bf16(const float* __restrict__ src, u16* __restrict__ hi,
                           u16* __restrict__ lo, int n) {
    int i = blockIdx.x * blockDim.x + threadIdx.x;
    if (i < n) {
        float f = src[i];
        u16 h = f2bf(f);
        hi[i] = h;
        lo[i] = f2bf(f - bf2f(h));
    }
}
__global__ void cvt_bf16(const float* __restrict__ src, u16* __restrict__ dst, int n) {
    int i = blockIdx.x * blockDim.x + threadIdx.x;
    if (i < n) dst[i] = f2bf(src[i]);
}

// ---------- fused QKV GEMM + l2-normalize + V-transpose ----------
// R13: m201-style 8-phase 256x256 schedule (T2+T3+T4+T5 combined; the regime
// table says T2/T5 only pay inside the phase-split schedule — R11/R12's
// 1-phase lockstep loops all pinned at MfmaUtil 34% = the m97 ceiling).
// Geometry: BM=BN=256, BK=64, 8 waves (2M x 4N), wave-tile 128x64 (FLOP per
// LDS-byte 44 vs 32 at 64x64), acc[8][4]. LDS 128KB = 2 K-tile buffers
// (even->buf0, odd->buf1), each A 32KB + B 32KB. Grid 32x12=384, 1 block/CU.
// Per K-tile: 4 phases, each = one C-quadrant(64x32) x K64 = 16 MFMA;
// ds_reads per phase 12/4/8/0; each phase stages ONE 16KB half-tile (2
// async16/thread) into the buffer whose last read was >=1 barrier-pair ago:
//   P0:rd Ah0+Bh0(buf0)  st A-h1(k1)->buf1   P4:rd(buf1) st A-h1(k2)->buf0
//   P1:rd Bh1(buf0)      st B-h0(k1)->buf1   P5:         st B-h0(k2)->buf0
//   P2:rd Ah1(buf0)      st B-h1(k1)->buf1   P6:         st B-h1(k2)->buf0
//   P3:(no rd)           st A-h0(k2)->buf0   P7:         st A-h0(k3)->buf1
// vmcnt(2) ONLY at P3/P7 (counted, never 0 in loop), placed before the
// mid-phase barrier so the barrier collectivizes the per-wave wait. Two
// asm s_barriers per phase (memory-clobber = scheduling fence). Swizzle:
// row stride is now 128B (=32 banks exactly -> 16-way conflict unswizzled);
// 16B-quad(0-7) ^= row&7, applied as pre-swizzled GLOBAL source + swizzled
// ds_read (involution both sides, rule 21) -> 2 lanes/bank (free).
// Prologue: stage K0+K1 (16 loads), vmcnt(8)+barrier. Tail: wrap-stages
// (dummy, benign). vmcnt(0) drain before epilogue.
#define QK_BUF 65536

#define QBAR() asm volatile("s_barrier" ::: "memory")

#define RD_AF(QH, BB) { \
    _Pragma("unroll") for (int mi = 0; mi < 4; ++mi) { \
        const int rr = wm + (QH) * 64 + mi * 16 + l16; \
        af[mi][0] = ld_bf16x8((const u16*)(lds + (BB) + rr * 128 + qsw0)); \
        af[mi][1] = ld_bf16x8((const u16*)(lds + (BB) + rr * 128 + qsw1)); } }

#define RD_BF(DST, NB, BB) { \
    _Pragma("unroll") for (int ni = 0; ni < 2; ++ni) { \
        const int rr = wn + (NB) * 32 + ni * 16 + l16; \
        DST[ni][0] = ld_bf16x8((const u16*)(lds + (BB) + 32768 + rr * 128 + qsw0)); \
        DST[ni][1] = ld_bf16x8((const u16*)(lds + (BB) + 32768 + rr * 128 + qsw1)); } }

#define ST_A(KT, H, BB) { \
    const char* g = aRow + (size_t)(H) * 262144 + (((KT) & 15) << 7); \
    char* d = lds + (BB) + (H) * 16384 + wave * 1024; \
    async16(g, d); async16(g + 131072, d + 8192); }

#define ST_B(KT, H, BB) { \
    const char* g = (((KT) < 16) ? bhRow : blRow) + (size_t)(H) * 262144 + (((KT) & 15) << 7); \
    char* d = lds + (BB) + 32768 + (H) * 16384 + wave * 1024; \
    async16(g, d); async16(g + 131072, d + 8192); }

#define MFMA_Q(MIB, NIB) { \
    __builtin_amdgcn_s_setprio(1); \
    _Pragma("unroll") for (int ks = 0; ks < 2; ++ks) \
    _Pragma("unroll") for (int mi = 0; mi < 4; ++mi) \
    _Pragma("unroll") for (int ni = 0; ni < 2; ++ni) \
        acc[(MIB) + mi][(NIB) + ni] = __builtin_amdgcn_mfma_f32_16x16x32_bf16( \
            af[mi][ks], ((NIB) ? b1 : b0)[ni][ks], acc[(MIB) + mi][(NIB) + ni], 0, 0, 0); \
    __builtin_amdgcn_s_setprio(0); }

__global__ __launch_bounds__(512, 2) void qkv_gemm(
    const u16* __restrict__ A,
    const u16* __restrict__ Bh, const u16* __restrict__ Bl,
    const float* __restrict__ bias,
    u16* __restrict__ Qn, u16* __restrict__ Kn, u16* __restrict__ Vt) {
    __shared__ __align__(1024) char lds[2 * QK_BUF];
    const int tid = threadIdx.x, wave = tid >> 6, lane = tid & 63;
    const int quad = lane >> 4, l16 = lane & 15;
    const int wm = (wave >> 2) * 128, wn = (wave & 3) * 64;
    const int m0 = blockIdx.x * 256, n0 = blockIdx.y * 256;

    // staging: half-tile = 128 rows x 64 elems = 16KB = 1024 chunks of 16B;
    // this thread covers chunks tid (rows 0-63) and tid+512 (rows 64-127).
    const int lr0 = tid >> 3;                       // 0..63
    const int qs = ((tid & 7) ^ (lr0 & 7)) * 16;    // swizzled src byte (64%8==0 -> same for +64 rows)
    const char* aRow  = (const char*)A  + (size_t)(m0 + lr0) * 2048 + qs;
    const char* bhRow = (const char*)Bh + (size_t)(n0 + lr0) * 2048 + qs;
    const char* blRow = (const char*)Bl + (size_t)(n0 + lr0) * 2048 + qs;

    // fragment-read swizzled quad offsets (row&7 == l16&7 for 16-aligned bases)
    const int qsw0 = ((0 * 4 + quad) ^ (l16 & 7)) * 16;
    const int qsw1 = ((1 * 4 + quad) ^ (l16 & 7)) * 16;

    f32x4 acc[8][4] = {};
    bf16x8 af[4][2], b0[2][2], b1[2][2];

    // prologue: K-tile 0 -> buf0, K-tile 1 -> buf1 (16 loads/thread-pairs)
    ST_A(0, 0, 0); ST_A(0, 1, 0); ST_B(0, 0, 0); ST_B(0, 1, 0);
    ST_A(1, 0, QK_BUF); ST_A(1, 1, QK_BUF); ST_B(1, 0, QK_BUF); ST_B(1, 1, QK_BUF);
    asm volatile("s_waitcnt vmcnt(8)" ::: "memory");   // K0 landed; K1 in flight
    QBAR();

    #pragma unroll 1
    for (int t = 0; t < 16; ++t) {
        const int k1 = 2 * t + 1;
        const int k2 = (2 * t + 2) & 31;
        const int k3 = (2 * t + 3) & 31;
        // ---- K-tile 2t (buf0) ----
        RD_AF(0, 0); RD_BF(b0, 0, 0);
        ST_A(k1, 1, QK_BUF);
        QBAR(); MFMA_Q(0, 0); QBAR();

        RD_BF(b1, 1, 0);
        ST_B(k1, 0, QK_BUF);
        QBAR(); MFMA_Q(0, 2); QBAR();

        RD_AF(1, 0);
        ST_B(k1, 1, QK_BUF);
        QBAR(); MFMA_Q(4, 0); QBAR();

        ST_A(k2, 0, 0);
        asm volatile("s_waitcnt vmcnt(2)" ::: "memory");  // buf1/k1 fully landed
        QBAR(); MFMA_Q(4, 2); QBAR();
        // ---- K-tile 2t+1 (buf1) ----
        RD_AF(0, QK_BUF); RD_BF(b0, 0, QK_BUF);
        ST_A(k2, 1, 0);
        QBAR(); MFMA_Q(0, 0); QBAR();

        RD_BF(b1, 1, QK_BUF);
        ST_B(k2, 0, 0);
        QBAR(); MFMA_Q(0, 2); QBAR();

        RD_AF(1, QK_BUF);
        ST_B(k2, 1, 0);
        QBAR(); MFMA_Q(4, 0); QBAR();

        ST_A(k3, 0, QK_BUF);
        asm volatile("s_waitcnt vmcnt(2)" ::: "memory");  // buf0/k2 fully landed
        QBAR(); MFMA_Q(4, 2); QBAR();
    }
    // drain: no in-flight DMA may outlive the workgroup's LDS
    asm volatile("s_waitcnt vmcnt(0)" ::: "memory");
    QBAR();

    #pragma unroll
    for (int ni = 0; ni < 4; ++ni) {
        const float bv = bias[n0 + wn + ni * 16 + l16];
        #pragma unroll
        for (int mi = 0; mi < 8; ++mi)
            #pragma unroll
            for (int r = 0; r < 4; ++r)
                acc[mi][ni][r] += bv;
    }

    if (n0 < 2048) {
        u16* dst = (n0 < 1024) ? Qn : Kn;
        const int hh = ((n0 & 1023) + wn) >> 6;
        #pragma unroll
        for (int mi = 0; mi < 8; ++mi) {
            float ss[4] = {};
            #pragma unroll
            for (int ni = 0; ni < 4; ++ni)
                #pragma unroll
                for (int r = 0; r < 4; ++r)
                    ss[r] += acc[mi][ni][r] * acc[mi][ni][r];
            #pragma unroll
            for (int r = 0; r < 4; ++r) {
                ss[r] += __shfl_xor(ss[r], 1);
                ss[r] += __shfl_xor(ss[r], 2);
                ss[r] += __shfl_xor(ss[r], 4);
                ss[r] += __shfl_xor(ss[r], 8);
                ss[r] = 1.f / fmaxf(sqrtf(ss[r]), 1e-12f);
            }
            const int mbase = m0 + wm + mi * 16 + quad * 4;
            const int b = mbase >> 11, n = mbase & 2047;
            #pragma unroll
            for (int r = 0; r < 4; ++r) {
                size_t rowoff = (((size_t)(b * HEADS + hh)) * NSEQ + n + r) * DH;
                #pragma unroll
                for (int ni = 0; ni < 4; ++ni)
                    dst[rowoff + ni * 16 + l16] = f2bf_n(acc[mi][ni][r] * ss[r]);
            }
        }
    } else {
        const int hh = ((n0 - 2048) + wn) >> 6;
        #pragma unroll
        for (int ni = 0; ni < 4; ++ni) {
            const int d = ni * 16 + l16;
            #pragma unroll
            for (int mi = 0; mi < 8; ++mi) {
                const int mbase = m0 + wm + mi * 16 + quad * 4;
                const int b = mbase >> 11, n = mbase & 2047;
                ushort4 t;
                t.x = f2bf_n(acc[mi][ni][0]);
                t.y = f2bf_n(acc[mi][ni][1]);
                t.z = f2bf_n(acc[mi][ni][2]);
                t.w = f2bf_n(acc[mi][ni][3]);
                *(ushort4*)&Vt[(((size_t)(b * HEADS + hh)) * DH + d) * NSEQ + n] = t;
            }
        }
    }
}

// ---------- out-proj GEMM: C[m,n] = sum_k A[m,k]*B[n,k], fp32 out ----------
__global__ __launch_bounds__(256) void out_gemm(
    const u16* __restrict__ A, const u16* __restrict__ B, float* __restrict__ C) {
    const int K = DMODEL, N = DMODEL, TK = 32;
    __shared__ __align__(16) u16 sA[128 * 32], sB[128 * 32];
    const int tid = threadIdx.x, wave = tid >> 6, lane = tid & 63;
    const int quad = lane >> 4, l16 = lane & 15;
    const int m0 = blockIdx.x * 128, n0 = blockIdx.y * 128;
    const int wm = (wave & 1) * 64, wn = (wave >> 1) * 64;
    f32x4 acc[4][4] = {};

    for (int k0 = 0; k0 < K; k0 += TK) {
        __syncthreads();
        #pragma unroll
        for (int pass = 0; pass < 2; ++pass) {
            const int c = pass * 256 + tid;
            const int row = c >> 2, part = c & 3;
            const int ldsOff = (pass * 256 + wave * 64) * 16;
            const size_t ga = (size_t)(m0 + row) * K + k0 + part * 8;
            const size_t gb = (size_t)(n0 + row) * K + k0 + part * 8;
            async16(A + ga, (const char*)sA + ldsOff);
            async16(B + gb, (const char*)sB + ldsOff);
        }
        __syncthreads();
        bf16x8 a[4];
        #pragma unroll
        for (int mt = 0; mt < 4; ++mt)
            a[mt] = ld_bf16x8(&sA[(wm + mt * 16 + l16) * TK + quad * 8]);
        #pragma unroll
        for (int nt = 0; nt < 4; ++nt) {
            bf16x8 b = ld_bf16x8(&sB[(wn + nt * 16 + l16) * TK + quad * 8]);
            #pragma unroll
            for (int mt = 0; mt < 4; ++mt)
                acc[mt][nt] = __builtin_amdgcn_mfma_f32_16x16x32_bf16(a[mt], b, acc[mt][nt], 0, 0, 0);
        }
    }
    #pragma unroll
    for (int nt = 0; nt < 4; ++nt) {
        const int n = n0 + wn + nt * 16 + l16;
        #pragma unroll
        for (int mt = 0; mt < 4; ++mt) {
            const int mbase = m0 + wm + mt * 16 + quad * 4;
            #pragma unroll
            for (int r = 0; r < 4; ++r)
                C[(size_t)(mbase + r) * N + n] = acc[mt][nt][r];
        }
    }
}

// ---------- flash attention, cosine specialization, 8-wave blocks ----------
// R10 winner, unchanged: T14 async-STAGE (reg double-buffer, counted vmcnt(2)
// across raw s_barriers), Ps pad 72, setprio around MFMA clusters.
__global__ __launch_bounds__(512) void flash_attn(
    const u16* __restrict__ Q, const u16* __restrict__ Kn, const u16* __restrict__ Vt,
    const float* __restrict__ lsc, u16* __restrict__ AO) {
    const int bh = blockIdx.x;
    const int q0 = blockIdx.y * 128;
    const int h = bh & (HEADS - 1), b = bh >> 4;
    const int tid = threadIdx.x, wave = tid >> 6, lane = tid & 63;
    const int quad = lane >> 4, l16 = lane & 15;
    const float scale = __expf(fminf(lsc[h], 4.6051702f));  // ln(100); here = 10
    const float c1 = scale * 1.4426950408889634f;           // scale*log2(e)

    __shared__ __align__(16) u16 Ks[64][72];      // [key][d]
    __shared__ __align__(16) u16 Vs[64][72];      // [d][key]
    __shared__ __align__(16) u16 Ps[8][16][72];   // per-wave P round-trip (C->A layout)

    const u16* qbase = Q + ((size_t)bh * NSEQ + q0 + wave * 16) * DH;
    bf16x8 qa[2];
    qa[0] = ld_bf16x8(qbase + l16 * DH + quad * 8);
    qa[1] = ld_bf16x8(qbase + l16 * DH + 32 + quad * 8);

    f32x4 O[4] = {};
    float lr[4] = {0.f, 0.f, 0.f, 0.f};

    const int row = tid >> 3, part = tid & 7;
    const u16* kb = Kn + (size_t)bh * NSEQ * DH + (size_t)row * DH + part * 8;
    const u16* vb = Vt + (size_t)bh * DH * NSEQ + (size_t)row * NSEQ + part * 8;

    // prologue: issue tile-0 loads (stay in flight until first ds_write)
    uint4 kA = *(const uint4*)kb;
    uint4 vA = *(const uint4*)vb;
    uint4 kB, vB;

    auto compute = [&]() {
        f32x4 S[4] = {};
        __builtin_amdgcn_s_setprio(1);
        #pragma unroll
        for (int nt = 0; nt < 4; ++nt) {
            bf16x8 k0 = ld_bf16x8(&Ks[nt * 16 + l16][quad * 8]);
            bf16x8 k1 = ld_bf16x8(&Ks[nt * 16 + l16][32 + quad * 8]);
            S[nt] = __builtin_amdgcn_mfma_f32_16x16x32_bf16(qa[0], k0, S[nt], 0, 0, 0);
            S[nt] = __builtin_amdgcn_mfma_f32_16x16x32_bf16(qa[1], k1, S[nt], 0, 0, 0);
        }
        __builtin_amdgcn_s_setprio(0);

        #pragma unroll
        for (int nt = 0; nt < 4; ++nt) {
            #pragma unroll
            for (int r = 0; r < 4; ++r) {
                float pv = __builtin_amdgcn_exp2f(__builtin_fmaf(S[nt][r], c1, -c1));
                lr[r] += pv;
                Ps[wave][quad * 4 + r][nt * 16 + l16] = f2bf_n(pv);
            }
        }
        asm volatile("s_waitcnt lgkmcnt(0)" ::: "memory");
        bf16x8 pa0 = ld_bf16x8(&Ps[wave][l16][quad * 8]);
        bf16x8 pa1 = ld_bf16x8(&Ps[wave][l16][32 + quad * 8]);

        __builtin_amdgcn_s_setprio(1);
        #pragma unroll
        for (int dt = 0; dt < 4; ++dt) {
            bf16x8 v0 = ld_bf16x8(&Vs[dt * 16 + l16][quad * 8]);
            bf16x8 v1 = ld_bf16x8(&Vs[dt * 16 + l16][32 + quad * 8]);
            O[dt] = __builtin_amdgcn_mfma_f32_16x16x32_bf16(pa0, v0, O[dt], 0, 0, 0);
            O[dt] = __builtin_amdgcn_mfma_f32_16x16x32_bf16(pa1, v1, O[dt], 0, 0, 0);
        }
        __builtin_amdgcn_s_setprio(0);
    };

    #pragma unroll 1
    for (int kt = 0; kt < NSEQ; kt += 128) {
        // ---- half 0: stage tile kt (regs A), prefetch kt+64 -> regs B ----
        asm volatile("s_waitcnt lgkmcnt(0)" ::: "memory");
        __builtin_amdgcn_s_barrier();                    // all waves done reading LDS
        kB = *(const uint4*)(kb + (size_t)(kt + 64) * DH);
        vB = *(const uint4*)(vb + (kt + 64));
        asm volatile("s_waitcnt vmcnt(2)" ::: "memory"); // tile-kt regs landed; 2 newer in flight
        *(uint4*)&Ks[row][part * 8] = kA;
        *(uint4*)&Vs[row][part * 8] = vA;
        asm volatile("s_waitcnt lgkmcnt(0)" ::: "memory");
        __builtin_amdgcn_s_barrier();                    // staging visible to all
        compute();

        // ---- half 1: stage tile kt+64 (regs B), prefetch kt+128 -> regs A ----
        asm volatile("s_waitcnt lgkmcnt(0)" ::: "memory");
        __builtin_amdgcn_s_barrier();
        {
            // last iteration: no tile kt+128 exists; re-read tile 0 (valid
            // memory, result unused) to keep the pipeline shape uniform.
            const int nk = (kt + 128) < NSEQ ? (kt + 128) : 0;
            kA = *(const uint4*)(kb + (size_t)nk * DH);
            vA = *(const uint4*)(vb + nk);
        }
        asm volatile("s_waitcnt vmcnt(2)" ::: "memory");
        *(uint4*)&Ks[row][part * 8] = kB;
        *(uint4*)&Vs[row][part * 8] = vB;
        asm volatile("s_waitcnt lgkmcnt(0)" ::: "memory");
        __builtin_amdgcn_s_barrier();
        compute();
    }

    #pragma unroll
    for (int r = 0; r < 4; ++r) {
        float s = lr[r];
        s += __shfl_xor(s, 1);
        s += __shfl_xor(s, 2);
        s += __shfl_xor(s, 4);
        s += __shfl_xor(s, 8);
        lr[r] = fmaxf(s, 1e-30f);
    }

    #pragma unroll
    for (int r = 0; r < 4; ++r) {
        float inv = 1.f / lr[r];
        size_t orow = (size_t)b * NSEQ + q0 + wave * 16 + quad * 4 + r;
        #pragma unroll
        for (int dt = 0; dt < 4; ++dt)
            AO[orow * DMODEL + h * DH + dt * 16 + l16] = f2bf_n(O[dt][r] * inv);
    }
}

// ---------- launch ----------
extern "C" void kernel_launch(void* const* d_in, const int* in_sizes, int n_in,
                              void* d_out, int out_size, void* d_ws, size_t ws_size,
                              hipStream_t stream) {
    const float* x    = (const float*)d_in[0];
    const float* wqkv = (const float*)d_in[1];
    const float* bqkv = (const float*)d_in[2];
    const float* wout = (const float*)d_in[3];
    const float* lsc  = (const float*)d_in[4];

    char* ws = (char*)d_ws;
    u16* xb   = (u16*)(ws + 0);           // 16 MB  (dead after qkv_gemm; aliased by AO)
    u16* wqh  = (u16*)(ws + 16777216);    // 6 MB
    u16* wql  = (u16*)(ws + 23068672);    // 6 MB
    u16* wob  = (u16*)(ws + 29360128);    // 2 MB
    u16* qn   = (u16*)(ws + 31457280);    // 16 MB [B,H,N,DH]
    u16* kn   = (u16*)(ws + 48234496);    // 16 MB
    u16* vt   = (u16*)(ws + 65011712);    // 16 MB [B,H,DH,N]
    u16* ao   = xb;                       // alias: [8192,1024] bf16

    cvt_bf16<<<MROWS * DMODEL / 256, 256, 0, stream>>>(x, xb, MROWS * DMODEL);
    split_bf16<<<NQKV * DMODEL / 256, 256, 0, stream>>>(wqkv, wqh, wql, NQKV * DMODEL);
    cvt_bf16<<<DMODEL * DMODEL / 256, 256, 0, stream>>>(wout, wob, DMODEL * DMODEL);

    qkv_gemm<<<dim3(MROWS / 256, NQKV / 256), 512, 0, stream>>>(xb, wqh, wql, bqkv, qn, kn, vt);
    flash_attn<<<dim3(BATCH * HEADS, NSEQ / 128), 512, 0, stream>>>(qn, kn, vt, lsc, ao);
    out_gemm<<<dim3(MROWS / 128, DMODEL / 128), 256, 0, stream>>>(ao, wob, (float*)d_out);
}

// Round 6
// 388.285 us; speedup vs baseline: 1.0718x; 1.0718x over previous
//
#include <hip/hip_runtime.h>

// ---------- types ----------
typedef __attribute__((ext_vector_type(8))) __bf16 bf16x8;
typedef __attribute__((ext_vector_type(4))) float f32x4;
typedef unsigned short u16;

__device__ __forceinline__ u16 f2bf(float f) {
    union { float f; unsigned u; } v; v.f = f;
    unsigned r = v.u + 0x7FFFu + ((v.u >> 16) & 1u);
    return (u16)(r >> 16);
}
__device__ __forceinline__ float bf2f(u16 h) {
    union { unsigned u; float f; } v; v.u = ((unsigned)h) << 16;
    return v.f;
}
// native cast: single v_cvt op (RNE)
__device__ __forceinline__ u16 f2bf_n(float f) {
    union { __bf16 b; u16 u; } t; t.b = (__bf16)f; return t.u;
}
__device__ __forceinline__ bf16x8 ld_bf16x8(const u16* p) {
    union { uint4 u; bf16x8 b; } t;
    t.u = *(const uint4*)p;
    return t.b;
}
__device__ __forceinline__ void async16(const void* g, const void* l) {
    __builtin_amdgcn_global_load_lds((const __attribute__((address_space(1))) void*)g,
                                     (__attribute__((address_space(3))) void*)l, 16, 0, 0);
}

// ---------- problem constants ----------
#define BATCH 4
#define NSEQ 2048
#define HEADS 16
#define DH 64
#define DMODEL 1024
#define MROWS 8192   // B*N
#define NQKV 3072

// ---------- elementwise ----------
__global__ void split_bf16(const float* __restrict__ src, u16* __restrict__ hi,
                           u16* __restrict__ lo, int n) {
    int i = blockIdx.x * blockDim.x + threadIdx.x;
    if (i < n) {
        float f = src[i];
        u16 h = f2bf(f);
        hi[i] = h;
        lo[i] = f2bf(f - bf2f(h));
    }
}
__global__ void cvt_bf16(const float* __restrict__ src, u16* __restrict__ dst, int n) {
    int i = blockIdx.x * blockDim.x + threadIdx.x;
    if (i < n) dst[i] = f2bf(src[i]);
}

// ---------- fused QKV GEMM + l2-normalize + V-transpose ----------
// R14: R13's 8-phase 256x256 schedule with the WAIT DEPTH fixed. R13 stalled
// (MfmaUtil 23%, VALU 11%) because vmcnt(2) at P3/P7 waited on stages issued
// 1-2 phases earlier (depth~1). Fixed stage placement derived from
// region-last-read times (buf0: B free after P1, A after P2; buf1: B after
// P5, A after P6):
//   P0: A(2t+1,h0)->buf1   P1: A(2t+1,h1)->buf1
//   P2: B(2t+2,h0)->buf0   P3: B(2t+2,h1)->buf0
//   P4: A(2t+2,h0)->buf0   P5: A(2t+2,h1)->buf0
//   P6: B(2t+3,h0)->buf1   P7: B(2t+3,h1)->buf1
// Waits: vmcnt(4) ONLY before the closing barriers of P3 and P7.
// Induction: end-P3 drains {P6p,P7p,P0,P1} = tile 2t+1 complete (first read
// P4), leaves [P2,P3]; end-P7 drains {P2..P5} = tile 2t+2 complete (first
// read next-P0), leaves [P6,P7]. Cover 2.3-5 phases per stage; count never
// hits 0 in the loop. Prologue: tile0 full + tile1 B-halves, vmcnt(4).
// Reads {12,4,8,0}/phase, 16-MFMA clusters, quad-XOR swizzle (conflicts=0,
// verified R13), setprio, epilogue: unchanged from R13 (absmax-verified).
#define QK_BUF 65536

#define QBAR() asm volatile("s_barrier" ::: "memory")

#define RD_AF(QH, BB) { \
    _Pragma("unroll") for (int mi = 0; mi < 4; ++mi) { \
        const int rr = wm + (QH) * 64 + mi * 16 + l16; \
        af[mi][0] = ld_bf16x8((const u16*)(lds + (BB) + rr * 128 + qsw0)); \
        af[mi][1] = ld_bf16x8((const u16*)(lds + (BB) + rr * 128 + qsw1)); } }

#define RD_BF(DST, NB, BB) { \
    _Pragma("unroll") for (int ni = 0; ni < 2; ++ni) { \
        const int rr = wn + (NB) * 32 + ni * 16 + l16; \
        DST[ni][0] = ld_bf16x8((const u16*)(lds + (BB) + 32768 + rr * 128 + qsw0)); \
        DST[ni][1] = ld_bf16x8((const u16*)(lds + (BB) + 32768 + rr * 128 + qsw1)); } }

#define ST_A(KT, H, BB) { \
    const char* g = aRow + (size_t)(H) * 262144 + (((KT) & 15) << 7); \
    char* d = lds + (BB) + (H) * 16384 + wave * 1024; \
    async16(g, d); async16(g + 131072, d + 8192); }

#define ST_B(KT, H, BB) { \
    const char* g = (((KT) < 16) ? bhRow : blRow) + (size_t)(H) * 262144 + (((KT) & 15) << 7); \
    char* d = lds + (BB) + 32768 + (H) * 16384 + wave * 1024; \
    async16(g, d); async16(g + 131072, d + 8192); }

#define MFMA_Q(MIB, NIB) { \
    __builtin_amdgcn_s_setprio(1); \
    _Pragma("unroll") for (int ks = 0; ks < 2; ++ks) \
    _Pragma("unroll") for (int mi = 0; mi < 4; ++mi) \
    _Pragma("unroll") for (int ni = 0; ni < 2; ++ni) \
        acc[(MIB) + mi][(NIB) + ni] = __builtin_amdgcn_mfma_f32_16x16x32_bf16( \
            af[mi][ks], ((NIB) ? b1 : b0)[ni][ks], acc[(MIB) + mi][(NIB) + ni], 0, 0, 0); \
    __builtin_amdgcn_s_setprio(0); }

#define VMW4() asm volatile("s_waitcnt vmcnt(4)" ::: "memory")

__global__ __launch_bounds__(512, 2) void qkv_gemm(
    const u16* __restrict__ A,
    const u16* __restrict__ Bh, const u16* __restrict__ Bl,
    const float* __restrict__ bias,
    u16* __restrict__ Qn, u16* __restrict__ Kn, u16* __restrict__ Vt) {
    __shared__ __align__(1024) char lds[2 * QK_BUF];
    const int tid = threadIdx.x, wave = tid >> 6, lane = tid & 63;
    const int quad = lane >> 4, l16 = lane & 15;
    const int wm = (wave >> 2) * 128, wn = (wave & 3) * 64;
    const int m0 = blockIdx.x * 256, n0 = blockIdx.y * 256;

    // staging: half-tile = 128 rows x 64 elems = 16KB; thread covers chunks
    // tid (rows 0-63) and tid+512 (rows 64-127).
    const int lr0 = tid >> 3;                       // 0..63
    const int qs = ((tid & 7) ^ (lr0 & 7)) * 16;    // swizzled src byte
    const char* aRow  = (const char*)A  + (size_t)(m0 + lr0) * 2048 + qs;
    const char* bhRow = (const char*)Bh + (size_t)(n0 + lr0) * 2048 + qs;
    const char* blRow = (const char*)Bl + (size_t)(n0 + lr0) * 2048 + qs;

    // fragment-read swizzled quad offsets (row&7 == l16&7 for 16-aligned bases)
    const int qsw0 = ((0 * 4 + quad) ^ (l16 & 7)) * 16;
    const int qsw1 = ((1 * 4 + quad) ^ (l16 & 7)) * 16;

    f32x4 acc[8][4] = {};
    bf16x8 af[4][2], b0[2][2], b1[2][2];

    // prologue: tile0 complete -> buf0 (8 loads), tile1 B-halves -> buf1 (4)
    ST_A(0, 0, 0); ST_A(0, 1, 0); ST_B(0, 0, 0); ST_B(0, 1, 0);
    ST_B(1, 0, QK_BUF); ST_B(1, 1, QK_BUF);
    VMW4();                                          // tile0 landed; tile1-B in flight
    QBAR();

    #pragma unroll 1
    for (int t = 0; t < 16; ++t) {
        const int k1 = 2 * t + 1;
        const int k2 = (2 * t + 2) & 31;
        const int k3 = (2 * t + 3) & 31;
        // ---- K-tile 2t (buf0) ----
        RD_AF(0, 0); RD_BF(b0, 0, 0);
        ST_A(k1, 0, QK_BUF);                          // buf1 A free (P6 prev)
        QBAR(); MFMA_Q(0, 0); QBAR();

        RD_BF(b1, 1, 0);
        ST_A(k1, 1, QK_BUF);
        QBAR(); MFMA_Q(0, 2); QBAR();

        RD_AF(1, 0);
        ST_B(k2, 0, 0);                               // buf0 B free (after P1)
        QBAR(); MFMA_Q(4, 0); QBAR();

        ST_B(k2, 1, 0);
        QBAR(); MFMA_Q(4, 2);
        VMW4();                                       // tile 2t+1 fully landed
        QBAR();
        // ---- K-tile 2t+1 (buf1) ----
        RD_AF(0, QK_BUF); RD_BF(b0, 0, QK_BUF);
        ST_A(k2, 0, 0);                               // buf0 A free (after P2)
        QBAR(); MFMA_Q(0, 0); QBAR();

        RD_BF(b1, 1, QK_BUF);
        ST_A(k2, 1, 0);
        QBAR(); MFMA_Q(0, 2); QBAR();

        RD_AF(1, QK_BUF);
        ST_B(k3, 0, QK_BUF);                          // buf1 B free (after P5)
        QBAR(); MFMA_Q(4, 0); QBAR();

        ST_B(k3, 1, QK_BUF);
        QBAR(); MFMA_Q(4, 2);
        VMW4();                                       // tile 2t+2 fully landed
        QBAR();
    }
    // drain: no in-flight DMA may outlive the workgroup's LDS
    asm volatile("s_waitcnt vmcnt(0)" ::: "memory");
    QBAR();

    #pragma unroll
    for (int ni = 0; ni < 4; ++ni) {
        const float bv = bias[n0 + wn + ni * 16 + l16];
        #pragma unroll
        for (int mi = 0; mi < 8; ++mi)
            #pragma unroll
            for (int r = 0; r < 4; ++r)
                acc[mi][ni][r] += bv;
    }

    if (n0 < 2048) {
        u16* dst = (n0 < 1024) ? Qn : Kn;
        const int hh = ((n0 & 1023) + wn) >> 6;
        #pragma unroll
        for (int mi = 0; mi < 8; ++mi) {
            float ss[4] = {};
            #pragma unroll
            for (int ni = 0; ni < 4; ++ni)
                #pragma unroll
                for (int r = 0; r < 4; ++r)
                    ss[r] += acc[mi][ni][r] * acc[mi][ni][r];
            #pragma unroll
            for (int r = 0; r < 4; ++r) {
                ss[r] += __shfl_xor(ss[r], 1);
                ss[r] += __shfl_xor(ss[r], 2);
                ss[r] += __shfl_xor(ss[r], 4);
                ss[r] += __shfl_xor(ss[r], 8);
                ss[r] = 1.f / fmaxf(sqrtf(ss[r]), 1e-12f);
            }
            const int mbase = m0 + wm + mi * 16 + quad * 4;
            const int b = mbase >> 11, n = mbase & 2047;
            #pragma unroll
            for (int r = 0; r < 4; ++r) {
                size_t rowoff = (((size_t)(b * HEADS + hh)) * NSEQ + n + r) * DH;
                #pragma unroll
                for (int ni = 0; ni < 4; ++ni)
                    dst[rowoff + ni * 16 + l16] = f2bf_n(acc[mi][ni][r] * ss[r]);
            }
        }
    } else {
        const int hh = ((n0 - 2048) + wn) >> 6;
        #pragma unroll
        for (int ni = 0; ni < 4; ++ni) {
            const int d = ni * 16 + l16;
            #pragma unroll
            for (int mi = 0; mi < 8; ++mi) {
                const int mbase = m0 + wm + mi * 16 + quad * 4;
                const int b = mbase >> 11, n = mbase & 2047;
                ushort4 t;
                t.x = f2bf_n(acc[mi][ni][0]);
                t.y = f2bf_n(acc[mi][ni][1]);
                t.z = f2bf_n(acc[mi][ni][2]);
                t.w = f2bf_n(acc[mi][ni][3]);
                *(ushort4*)&Vt[(((size_t)(b * HEADS + hh)) * DH + d) * NSEQ + n] = t;
            }
        }
    }
}

// ---------- out-proj GEMM: C[m,n] = sum_k A[m,k]*B[n,k], fp32 out ----------
__global__ __launch_bounds__(256) void out_gemm(
    const u16* __restrict__ A, const u16* __restrict__ B, float* __restrict__ C) {
    const int K = DMODEL, N = DMODEL, TK = 32;
    __shared__ __align__(16) u16 sA[128 * 32], sB[128 * 32];
    const int tid = threadIdx.x, wave = tid >> 6, lane = tid & 63;
    const int quad = lane >> 4, l16 = lane & 15;
    const int m0 = blockIdx.x * 128, n0 = blockIdx.y * 128;
    const int wm = (wave & 1) * 64, wn = (wave >> 1) * 64;
    f32x4 acc[4][4] = {};

    for (int k0 = 0; k0 < K; k0 += TK) {
        __syncthreads();
        #pragma unroll
        for (int pass = 0; pass < 2; ++pass) {
            const int c = pass * 256 + tid;
            const int row = c >> 2, part = c & 3;
            const int ldsOff = (pass * 256 + wave * 64) * 16;
            const size_t ga = (size_t)(m0 + row) * K + k0 + part * 8;
            const size_t gb = (size_t)(n0 + row) * K + k0 + part * 8;
            async16(A + ga, (const char*)sA + ldsOff);
            async16(B + gb, (const char*)sB + ldsOff);
        }
        __syncthreads();
        bf16x8 a[4];
        #pragma unroll
        for (int mt = 0; mt < 4; ++mt)
            a[mt] = ld_bf16x8(&sA[(wm + mt * 16 + l16) * TK + quad * 8]);
        #pragma unroll
        for (int nt = 0; nt < 4; ++nt) {
            bf16x8 b = ld_bf16x8(&sB[(wn + nt * 16 + l16) * TK + quad * 8]);
            #pragma unroll
            for (int mt = 0; mt < 4; ++mt)
                acc[mt][nt] = __builtin_amdgcn_mfma_f32_16x16x32_bf16(a[mt], b, acc[mt][nt], 0, 0, 0);
        }
    }
    #pragma unroll
    for (int nt = 0; nt < 4; ++nt) {
        const int n = n0 + wn + nt * 16 + l16;
        #pragma unroll
        for (int mt = 0; mt < 4; ++mt) {
            const int mbase = m0 + wm + mt * 16 + quad * 4;
            #pragma unroll
            for (int r = 0; r < 4; ++r)
                C[(size_t)(mbase + r) * N + n] = acc[mt][nt][r];
        }
    }
}

// ---------- flash attention, cosine specialization, 8-wave blocks ----------
// R10 winner, unchanged: T14 async-STAGE (reg double-buffer, counted vmcnt(2)
// across raw s_barriers), Ps pad 72, setprio around MFMA clusters.
__global__ __launch_bounds__(512) void flash_attn(
    const u16* __restrict__ Q, const u16* __restrict__ Kn, const u16* __restrict__ Vt,
    const float* __restrict__ lsc, u16* __restrict__ AO) {
    const int bh = blockIdx.x;
    const int q0 = blockIdx.y * 128;
    const int h = bh & (HEADS - 1), b = bh >> 4;
    const int tid = threadIdx.x, wave = tid >> 6, lane = tid & 63;
    const int quad = lane >> 4, l16 = lane & 15;
    const float scale = __expf(fminf(lsc[h], 4.6051702f));  // ln(100); here = 10
    const float c1 = scale * 1.4426950408889634f;           // scale*log2(e)

    __shared__ __align__(16) u16 Ks[64][72];      // [key][d]
    __shared__ __align__(16) u16 Vs[64][72];      // [d][key]
    __shared__ __align__(16) u16 Ps[8][16][72];   // per-wave P round-trip (C->A layout)

    const u16* qbase = Q + ((size_t)bh * NSEQ + q0 + wave * 16) * DH;
    bf16x8 qa[2];
    qa[0] = ld_bf16x8(qbase + l16 * DH + quad * 8);
    qa[1] = ld_bf16x8(qbase + l16 * DH + 32 + quad * 8);

    f32x4 O[4] = {};
    float lr[4] = {0.f, 0.f, 0.f, 0.f};

    const int row = tid >> 3, part = tid & 7;
    const u16* kb = Kn + (size_t)bh * NSEQ * DH + (size_t)row * DH + part * 8;
    const u16* vb = Vt + (size_t)bh * DH * NSEQ + (size_t)row * NSEQ + part * 8;

    // prologue: issue tile-0 loads (stay in flight until first ds_write)
    uint4 kA = *(const uint4*)kb;
    uint4 vA = *(const uint4*)vb;
    uint4 kB, vB;

    auto compute = [&]() {
        f32x4 S[4] = {};
        __builtin_amdgcn_s_setprio(1);
        #pragma unroll
        for (int nt = 0; nt < 4; ++nt) {
            bf16x8 k0 = ld_bf16x8(&Ks[nt * 16 + l16][quad * 8]);
            bf16x8 k1 = ld_bf16x8(&Ks[nt * 16 + l16][32 + quad * 8]);
            S[nt] = __builtin_amdgcn_mfma_f32_16x16x32_bf16(qa[0], k0, S[nt], 0, 0, 0);
            S[nt] = __builtin_amdgcn_mfma_f32_16x16x32_bf16(qa[1], k1, S[nt], 0, 0, 0);
        }
        __builtin_amdgcn_s_setprio(0);

        #pragma unroll
        for (int nt = 0; nt < 4; ++nt) {
            #pragma unroll
            for (int r = 0; r < 4; ++r) {
                float pv = __builtin_amdgcn_exp2f(__builtin_fmaf(S[nt][r], c1, -c1));
                lr[r] += pv;
                Ps[wave][quad * 4 + r][nt * 16 + l16] = f2bf_n(pv);
            }
        }
        asm volatile("s_waitcnt lgkmcnt(0)" ::: "memory");
        bf16x8 pa0 = ld_bf16x8(&Ps[wave][l16][quad * 8]);
        bf16x8 pa1 = ld_bf16x8(&Ps[wave][l16][32 + quad * 8]);

        __builtin_amdgcn_s_setprio(1);
        #pragma unroll
        for (int dt = 0; dt < 4; ++dt) {
            bf16x8 v0 = ld_bf16x8(&Vs[dt * 16 + l16][quad * 8]);
            bf16x8 v1 = ld_bf16x8(&Vs[dt * 16 + l16][32 + quad * 8]);
            O[dt] = __builtin_amdgcn_mfma_f32_16x16x32_bf16(pa0, v0, O[dt], 0, 0, 0);
            O[dt] = __builtin_amdgcn_mfma_f32_16x16x32_bf16(pa1, v1, O[dt], 0, 0, 0);
        }
        __builtin_amdgcn_s_setprio(0);
    };

    #pragma unroll 1
    for (int kt = 0; kt < NSEQ; kt += 128) {
        // ---- half 0: stage tile kt (regs A), prefetch kt+64 -> regs B ----
        asm volatile("s_waitcnt lgkmcnt(0)" ::: "memory");
        __builtin_amdgcn_s_barrier();                    // all waves done reading LDS
        kB = *(const uint4*)(kb + (size_t)(kt + 64) * DH);
        vB = *(const uint4*)(vb + (kt + 64));
        asm volatile("s_waitcnt vmcnt(2)" ::: "memory"); // tile-kt regs landed; 2 newer in flight
        *(uint4*)&Ks[row][part * 8] = kA;
        *(uint4*)&Vs[row][part * 8] = vA;
        asm volatile("s_waitcnt lgkmcnt(0)" ::: "memory");
        __builtin_amdgcn_s_barrier();                    // staging visible to all
        compute();

        // ---- half 1: stage tile kt+64 (regs B), prefetch kt+128 -> regs A ----
        asm volatile("s_waitcnt lgkmcnt(0)" ::: "memory");
        __builtin_amdgcn_s_barrier();
        {
            // last iteration: no tile kt+128 exists; re-read tile 0 (valid
            // memory, result unused) to keep the pipeline shape uniform.
            const int nk = (kt + 128) < NSEQ ? (kt + 128) : 0;
            kA = *(const uint4*)(kb + (size_t)nk * DH);
            vA = *(const uint4*)(vb + nk);
        }
        asm volatile("s_waitcnt vmcnt(2)" ::: "memory");
        *(uint4*)&Ks[row][part * 8] = kB;
        *(uint4*)&Vs[row][part * 8] = vB;
        asm volatile("s_waitcnt lgkmcnt(0)" ::: "memory");
        __builtin_amdgcn_s_barrier();
        compute();
    }

    #pragma unroll
    for (int r = 0; r < 4; ++r) {
        float s = lr[r];
        s += __shfl_xor(s, 1);
        s += __shfl_xor(s, 2);
        s += __shfl_xor(s, 4);
        s += __shfl_xor(s, 8);
        lr[r] = fmaxf(s, 1e-30f);
    }

    #pragma unroll
    for (int r = 0; r < 4; ++r) {
        float inv = 1.f / lr[r];
        size_t orow = (size_t)b * NSEQ + q0 + wave * 16 + quad * 4 + r;
        #pragma unroll
        for (int dt = 0; dt < 4; ++dt)
            AO[orow * DMODEL + h * DH + dt * 16 + l16] = f2bf_n(O[dt][r] * inv);
    }
}

// ---------- launch ----------
extern "C" void kernel_launch(void* const* d_in, const int* in_sizes, int n_in,
                              void* d_out, int out_size, void* d_ws, size_t ws_size,
                              hipStream_t stream) {
    const float* x    = (const float*)d_in[0];
    const float* wqkv = (const float*)d_in[1];
    const float* bqkv = (const float*)d_in[2];
    const float* wout = (const float*)d_in[3];
    const float* lsc  = (const float*)d_in[4];

    char* ws = (char*)d_ws;
    u16* xb   = (u16*)(ws + 0);           // 16 MB  (dead after qkv_gemm; aliased by AO)
    u16* wqh  = (u16*)(ws + 16777216);    // 6 MB
    u16* wql  = (u16*)(ws + 23068672);    // 6 MB
    u16* wob  = (u16*)(ws + 29360128);    // 2 MB
    u16* qn   = (u16*)(ws + 31457280);    // 16 MB [B,H,N,DH]
    u16* kn   = (u16*)(ws + 48234496);    // 16 MB
    u16* vt   = (u16*)(ws + 65011712);    // 16 MB [B,H,DH,N]
    u16* ao   = xb;                       // alias: [8192,1024] bf16

    cvt_bf16<<<MROWS * DMODEL / 256, 256, 0, stream>>>(x, xb, MROWS * DMODEL);
    split_bf16<<<NQKV * DMODEL / 256, 256, 0, stream>>>(wqkv, wqh, wql, NQKV * DMODEL);
    cvt_bf16<<<DMODEL * DMODEL / 256, 256, 0, stream>>>(wout, wob, DMODEL * DMODEL);

    qkv_gemm<<<dim3(MROWS / 256, NQKV / 256), 512, 0, stream>>>(xb, wqh, wql, bqkv, qn, kn, vt);
    flash_attn<<<dim3(BATCH * HEADS, NSEQ / 128), 512, 0, stream>>>(qn, kn, vt, lsc, ao);
    out_gemm<<<dim3(MROWS / 128, DMODEL / 128), 256, 0, stream>>>(ao, wob, (float*)d_out);
}

// Round 7
// 358.605 us; speedup vs baseline: 1.1605x; 1.0828x over previous
//
#include <hip/hip_runtime.h>

// ---------- types ----------
typedef __attribute__((ext_vector_type(8))) __bf16 bf16x8;
typedef __attribute__((ext_vector_type(4))) float f32x4;
typedef unsigned short u16;

__device__ __forceinline__ u16 f2bf(float f) {
    union { float f; unsigned u; } v; v.f = f;
    unsigned r = v.u + 0x7FFFu + ((v.u >> 16) & 1u);
    return (u16)(r >> 16);
}
__device__ __forceinline__ float bf2f(u16 h) {
    union { unsigned u; float f; } v; v.u = ((unsigned)h) << 16;
    return v.f;
}
// native cast: single v_cvt op (RNE)
__device__ __forceinline__ u16 f2bf_n(float f) {
    union { __bf16 b; u16 u; } t; t.b = (__bf16)f; return t.u;
}
__device__ __forceinline__ bf16x8 ld_bf16x8(const u16* p) {
    union { uint4 u; bf16x8 b; } t;
    t.u = *(const uint4*)p;
    return t.b;
}
__device__ __forceinline__ void async16(const void* g, const void* l) {
    __builtin_amdgcn_global_load_lds((const __attribute__((address_space(1))) void*)g,
                                     (__attribute__((address_space(3))) void*)l, 16, 0, 0);
}

// ---------- problem constants ----------
#define BATCH 4
#define NSEQ 2048
#define HEADS 16
#define DH 64
#define DMODEL 1024
#define MROWS 8192   // B*N
#define NQKV 3072
#define XE 8388608   // MROWS*DMODEL
#define WE 3145728   // NQKV*DMODEL
#define OE 1048576   // DMODEL*DMODEL

// ---------- fused elementwise prep (R15: 3 launches -> 1) ----------
__global__ __launch_bounds__(256) void prep(
    const float* __restrict__ x, const float* __restrict__ wqkv,
    const float* __restrict__ wout,
    u16* __restrict__ xb, u16* __restrict__ wqh, u16* __restrict__ wql,
    u16* __restrict__ wob) {
    const int i4 = (blockIdx.x * 256 + threadIdx.x) * 4;
    if (i4 < XE) {
        float4 v = *(const float4*)(x + i4);
        ushort4 t = { f2bf(v.x), f2bf(v.y), f2bf(v.z), f2bf(v.w) };
        *(ushort4*)(xb + i4) = t;
    } else if (i4 < XE + WE) {
        const int j = i4 - XE;
        float4 v = *(const float4*)(wqkv + j);
        ushort4 h = { f2bf(v.x), f2bf(v.y), f2bf(v.z), f2bf(v.w) };
        ushort4 l = { f2bf(v.x - bf2f(h.x)), f2bf(v.y - bf2f(h.y)),
                      f2bf(v.z - bf2f(h.z)), f2bf(v.w - bf2f(h.w)) };
        *(ushort4*)(wqh + j) = h;
        *(ushort4*)(wql + j) = l;
    } else {
        const int j = i4 - XE - WE;
        float4 v = *(const float4*)(wout + j);
        ushort4 t = { f2bf(v.x), f2bf(v.y), f2bf(v.z), f2bf(v.w) };
        *(ushort4*)(wob + j) = t;
    }
}

// ---------- fused QKV GEMM + l2-normalize + V-transpose ----------
// R15: REVERT to the R7/R10 winner (131.5us measured). The 8-phase schedule
// was falsified for this shape (R13: 179us, R14 wait-depth-fixed: 157.7us,
// both MfmaUtil<27% vs this structure's 34%) — with 1 block/CU there is no
// cross-block overlap to absorb 16 barriers/K-tile. This 2-barrier loop at
// 3+ blocks/CU gets barrier overlap across blocks for free (m114).
__global__ __launch_bounds__(256) void qkv_gemm(
    const u16* __restrict__ A,
    const u16* __restrict__ Bh, const u16* __restrict__ Bl,
    const float* __restrict__ bias,
    u16* __restrict__ Qn, u16* __restrict__ Kn, u16* __restrict__ Vt) {
    const int K = DMODEL, TK = 32;
    __shared__ __align__(16) u16 sA[128 * 32];
    __shared__ __align__(16) u16 sBh[128 * 32], sBl[128 * 32];
    const int tid = threadIdx.x, wave = tid >> 6, lane = tid & 63;
    const int quad = lane >> 4, l16 = lane & 15;
    const int m0 = blockIdx.x * 128, n0 = blockIdx.y * 128;
    const int wm = (wave & 1) * 64, wn = (wave >> 1) * 64;
    f32x4 acc[4][4] = {};

    for (int k0 = 0; k0 < K; k0 += TK) {
        __syncthreads();
        #pragma unroll
        for (int pass = 0; pass < 2; ++pass) {
            const int c = pass * 256 + tid;
            const int row = c >> 2, part = c & 3;
            const int ldsOff = (pass * 256 + wave * 64) * 16;  // bytes; dest = base + lane*16
            const size_t ga = (size_t)(m0 + row) * K + k0 + part * 8;
            const size_t gb = (size_t)(n0 + row) * K + k0 + part * 8;
            async16(A + ga, (const char*)sA + ldsOff);
            async16(Bh + gb, (const char*)sBh + ldsOff);
            async16(Bl + gb, (const char*)sBl + ldsOff);
        }
        __syncthreads();
        bf16x8 a[4];
        #pragma unroll
        for (int mt = 0; mt < 4; ++mt)
            a[mt] = ld_bf16x8(&sA[(wm + mt * 16 + l16) * TK + quad * 8]);
        #pragma unroll
        for (int nt = 0; nt < 4; ++nt) {
            const int cix = wn + nt * 16 + l16;
            bf16x8 bh = ld_bf16x8(&sBh[cix * TK + quad * 8]);
            bf16x8 bl = ld_bf16x8(&sBl[cix * TK + quad * 8]);
            #pragma unroll
            for (int mt = 0; mt < 4; ++mt) {
                acc[mt][nt] = __builtin_amdgcn_mfma_f32_16x16x32_bf16(a[mt], bh, acc[mt][nt], 0, 0, 0);
                acc[mt][nt] = __builtin_amdgcn_mfma_f32_16x16x32_bf16(a[mt], bl, acc[mt][nt], 0, 0, 0);
            }
        }
    }

    #pragma unroll
    for (int nt = 0; nt < 4; ++nt) {
        const float bv = bias[n0 + wn + nt * 16 + l16];
        #pragma unroll
        for (int mt = 0; mt < 4; ++mt)
            #pragma unroll
            for (int r = 0; r < 4; ++r)
                acc[mt][nt][r] += bv;
    }

    if (n0 < 2048) {
        u16* dst = (n0 < 1024) ? Qn : Kn;
        const int nq = (n0 & 1023) + wn;
        const int hh = nq >> 6;
        #pragma unroll
        for (int mt = 0; mt < 4; ++mt) {
            float ss[4] = {};
            #pragma unroll
            for (int nt = 0; nt < 4; ++nt)
                #pragma unroll
                for (int r = 0; r < 4; ++r)
                    ss[r] += acc[mt][nt][r] * acc[mt][nt][r];
            #pragma unroll
            for (int r = 0; r < 4; ++r) {
                ss[r] += __shfl_xor(ss[r], 1);
                ss[r] += __shfl_xor(ss[r], 2);
                ss[r] += __shfl_xor(ss[r], 4);
                ss[r] += __shfl_xor(ss[r], 8);
                ss[r] = 1.f / fmaxf(sqrtf(ss[r]), 1e-12f);
            }
            const int mbase = m0 + wm + mt * 16 + quad * 4;
            const int b = mbase >> 11, n = mbase & 2047;
            #pragma unroll
            for (int r = 0; r < 4; ++r) {
                size_t rowoff = (((size_t)(b * HEADS + hh)) * NSEQ + n + r) * DH;
                #pragma unroll
                for (int nt = 0; nt < 4; ++nt)
                    dst[rowoff + nt * 16 + l16] = f2bf_n(acc[mt][nt][r] * ss[r]);
            }
        }
    } else {
        const int nv = (n0 - 2048) + wn;
        const int hh = nv >> 6;
        #pragma unroll
        for (int nt = 0; nt < 4; ++nt) {
            const int d = nt * 16 + l16;
            #pragma unroll
            for (int mt = 0; mt < 4; ++mt) {
                const int mbase = m0 + wm + mt * 16 + quad * 4;
                const int b = mbase >> 11, n = mbase & 2047;
                ushort4 t;
                t.x = f2bf_n(acc[mt][nt][0]);
                t.y = f2bf_n(acc[mt][nt][1]);
                t.z = f2bf_n(acc[mt][nt][2]);
                t.w = f2bf_n(acc[mt][nt][3]);
                *(ushort4*)&Vt[(((size_t)(b * HEADS + hh)) * DH + d) * NSEQ + n] = t;
            }
        }
    }
}

// ---------- out-proj GEMM: C[m,n] = sum_k A[m,k]*B[n,k], fp32 out ----------
__global__ __launch_bounds__(256) void out_gemm(
    const u16* __restrict__ A, const u16* __restrict__ B, float* __restrict__ C) {
    const int K = DMODEL, N = DMODEL, TK = 32;
    __shared__ __align__(16) u16 sA[128 * 32], sB[128 * 32];
    const int tid = threadIdx.x, wave = tid >> 6, lane = tid & 63;
    const int quad = lane >> 4, l16 = lane & 15;
    const int m0 = blockIdx.x * 128, n0 = blockIdx.y * 128;
    const int wm = (wave & 1) * 64, wn = (wave >> 1) * 64;
    f32x4 acc[4][4] = {};

    for (int k0 = 0; k0 < K; k0 += TK) {
        __syncthreads();
        #pragma unroll
        for (int pass = 0; pass < 2; ++pass) {
            const int c = pass * 256 + tid;
            const int row = c >> 2, part = c & 3;
            const int ldsOff = (pass * 256 + wave * 64) * 16;
            const size_t ga = (size_t)(m0 + row) * K + k0 + part * 8;
            const size_t gb = (size_t)(n0 + row) * K + k0 + part * 8;
            async16(A + ga, (const char*)sA + ldsOff);
            async16(B + gb, (const char*)sB + ldsOff);
        }
        __syncthreads();
        bf16x8 a[4];
        #pragma unroll
        for (int mt = 0; mt < 4; ++mt)
            a[mt] = ld_bf16x8(&sA[(wm + mt * 16 + l16) * TK + quad * 8]);
        #pragma unroll
        for (int nt = 0; nt < 4; ++nt) {
            bf16x8 b = ld_bf16x8(&sB[(wn + nt * 16 + l16) * TK + quad * 8]);
            #pragma unroll
            for (int mt = 0; mt < 4; ++mt)
                acc[mt][nt] = __builtin_amdgcn_mfma_f32_16x16x32_bf16(a[mt], b, acc[mt][nt], 0, 0, 0);
        }
    }
    #pragma unroll
    for (int nt = 0; nt < 4; ++nt) {
        const int n = n0 + wn + nt * 16 + l16;
        #pragma unroll
        for (int mt = 0; mt < 4; ++mt) {
            const int mbase = m0 + wm + mt * 16 + quad * 4;
            #pragma unroll
            for (int r = 0; r < 4; ++r)
                C[(size_t)(mbase + r) * N + n] = acc[mt][nt][r];
        }
    }
}

// ---------- flash attention, cosine specialization, 8-wave blocks ----------
// R15: T12 swapped-QK^T in-register softmax. Compute mfma(K,Q) (same frag
// loads — A/B layouts are index-identical — operand order swapped), so lane
// holds P for ONE q=l16: S2[nt] C-layout = [key=nt*16+quad*4+r][q=l16].
// The Ps LDS round-trip (16 ds_write_b16 + lgkmcnt(0) drain + 2 ds_read,
// twice-serial per tile) is replaced by 8 v_cvt_pk_bf16_f32 + 16 __shfl:
// PV A-frag u32 j of k-chunk kc covers keys 32kc+8q+2j = tile nt=2kc+(q>>1),
// src quad qs=2(q&1)+(j>>1), pair p=j&1 (algebra: nt*16+qs*4+2p =
// 32kc+8q+2j, checked). Row-sum becomes lane-local + xor16/xor32 at end;
// per-q divisor fetched by one shfl per r. Ps deleted (-18KB LDS).
// Keeps R10's T14 staging (counted vmcnt(2) across raw barriers) + setprio.
__global__ __launch_bounds__(512) void flash_attn(
    const u16* __restrict__ Q, const u16* __restrict__ Kn, const u16* __restrict__ Vt,
    const float* __restrict__ lsc, u16* __restrict__ AO) {
    const int bh = blockIdx.x;
    const int q0 = blockIdx.y * 128;
    const int h = bh & (HEADS - 1), b = bh >> 4;
    const int tid = threadIdx.x, wave = tid >> 6, lane = tid & 63;
    const int quad = lane >> 4, l16 = lane & 15;
    const float scale = __expf(fminf(lsc[h], 4.6051702f));  // ln(100); here = 10
    const float c1 = scale * 1.4426950408889634f;           // scale*log2(e)

    __shared__ __align__(16) u16 Ks[64][72];      // [key][d]
    __shared__ __align__(16) u16 Vs[64][72];      // [d][key]

    const u16* qbase = Q + ((size_t)bh * NSEQ + q0 + wave * 16) * DH;
    bf16x8 qa[2];
    qa[0] = ld_bf16x8(qbase + l16 * DH + quad * 8);
    qa[1] = ld_bf16x8(qbase + l16 * DH + 32 + quad * 8);

    f32x4 O[4] = {};
    float lrs = 0.f;

    const int row = tid >> 3, part = tid & 7;
    const u16* kb = Kn + (size_t)bh * NSEQ * DH + (size_t)row * DH + part * 8;
    const u16* vb = Vt + (size_t)bh * DH * NSEQ + (size_t)row * NSEQ + part * 8;

    // prologue: issue tile-0 loads (stay in flight until first ds_write)
    uint4 kA = *(const uint4*)kb;
    uint4 vA = *(const uint4*)vb;
    uint4 kB, vB;

    auto compute = [&]() {
        f32x4 S[4] = {};
        __builtin_amdgcn_s_setprio(1);
        #pragma unroll
        for (int nt = 0; nt < 4; ++nt) {
            bf16x8 k0 = ld_bf16x8(&Ks[nt * 16 + l16][quad * 8]);
            bf16x8 k1 = ld_bf16x8(&Ks[nt * 16 + l16][32 + quad * 8]);
            S[nt] = __builtin_amdgcn_mfma_f32_16x16x32_bf16(k0, qa[0], S[nt], 0, 0, 0);
            S[nt] = __builtin_amdgcn_mfma_f32_16x16x32_bf16(k1, qa[1], S[nt], 0, 0, 0);
        }
        __builtin_amdgcn_s_setprio(0);

        unsigned w[4][2];
        #pragma unroll
        for (int nt = 0; nt < 4; ++nt) {
            #pragma unroll
            for (int p = 0; p < 2; ++p) {
                float a = __builtin_amdgcn_exp2f(__builtin_fmaf(S[nt][2 * p], c1, -c1));
                float c = __builtin_amdgcn_exp2f(__builtin_fmaf(S[nt][2 * p + 1], c1, -c1));
                lrs += a + c;
                asm("v_cvt_pk_bf16_f32 %0, %1, %2" : "=v"(w[nt][p]) : "v"(a), "v"(c));
            }
        }
        // redistribute to PV A-fragments (all in-register)
        bf16x8 pf[2];
        #pragma unroll
        for (int kc = 0; kc < 2; ++kc) {
            union { unsigned u[4]; bf16x8 b; } t;
            #pragma unroll
            for (int j = 0; j < 4; ++j) {
                const int src = l16 + (2 * (quad & 1) + (j >> 1)) * 16;
                unsigned lo = (unsigned)__shfl((int)w[2 * kc][j & 1], src);
                unsigned hi = (unsigned)__shfl((int)w[2 * kc + 1][j & 1], src);
                t.u[j] = (quad & 2) ? hi : lo;
            }
            pf[kc] = t.b;
        }

        __builtin_amdgcn_s_setprio(1);
        #pragma unroll
        for (int dt = 0; dt < 4; ++dt) {
            bf16x8 v0 = ld_bf16x8(&Vs[dt * 16 + l16][quad * 8]);
            bf16x8 v1 = ld_bf16x8(&Vs[dt * 16 + l16][32 + quad * 8]);
            O[dt] = __builtin_amdgcn_mfma_f32_16x16x32_bf16(pf[0], v0, O[dt], 0, 0, 0);
            O[dt] = __builtin_amdgcn_mfma_f32_16x16x32_bf16(pf[1], v1, O[dt], 0, 0, 0);
        }
        __builtin_amdgcn_s_setprio(0);
    };

    #pragma unroll 1
    for (int kt = 0; kt < NSEQ; kt += 128) {
        // ---- half 0: stage tile kt (regs A), prefetch kt+64 -> regs B ----
        asm volatile("s_waitcnt lgkmcnt(0)" ::: "memory");
        __builtin_amdgcn_s_barrier();                    // all waves done reading LDS
        kB = *(const uint4*)(kb + (size_t)(kt + 64) * DH);
        vB = *(const uint4*)(vb + (kt + 64));
        asm volatile("s_waitcnt vmcnt(2)" ::: "memory"); // tile-kt regs landed; 2 newer in flight
        *(uint4*)&Ks[row][part * 8] = kA;
        *(uint4*)&Vs[row][part * 8] = vA;
        asm volatile("s_waitcnt lgkmcnt(0)" ::: "memory");
        __builtin_amdgcn_s_barrier();                    // staging visible to all
        compute();

        // ---- half 1: stage tile kt+64 (regs B), prefetch kt+128 -> regs A ----
        asm volatile("s_waitcnt lgkmcnt(0)" ::: "memory");
        __builtin_amdgcn_s_barrier();
        {
            // last iteration: no tile kt+128 exists; re-read tile 0 (valid
            // memory, result unused) to keep the pipeline shape uniform.
            const int nk = (kt + 128) < NSEQ ? (kt + 128) : 0;
            kA = *(const uint4*)(kb + (size_t)nk * DH);
            vA = *(const uint4*)(vb + nk);
        }
        asm volatile("s_waitcnt vmcnt(2)" ::: "memory");
        *(uint4*)&Ks[row][part * 8] = kB;
        *(uint4*)&Vs[row][part * 8] = vB;
        asm volatile("s_waitcnt lgkmcnt(0)" ::: "memory");
        __builtin_amdgcn_s_barrier();
        compute();
    }

    // denominator: sum over quads (each lane has partial for q=l16)
    lrs += __shfl_xor(lrs, 16);
    lrs += __shfl_xor(lrs, 32);

    #pragma unroll
    for (int r = 0; r < 4; ++r) {
        const float lq = __shfl(lrs, quad * 4 + r);      // total for q=quad*4+r
        const float inv = 1.f / fmaxf(lq, 1e-30f);
        size_t orow = (size_t)b * NSEQ + q0 + wave * 16 + quad * 4 + r;
        #pragma unroll
        for (int dt = 0; dt < 4; ++dt)
            AO[orow * DMODEL + h * DH + dt * 16 + l16] = f2bf_n(O[dt][r] * inv);
    }
}

// ---------- launch ----------
extern "C" void kernel_launch(void* const* d_in, const int* in_sizes, int n_in,
                              void* d_out, int out_size, void* d_ws, size_t ws_size,
                              hipStream_t stream) {
    const float* x    = (const float*)d_in[0];
    const float* wqkv = (const float*)d_in[1];
    const float* bqkv = (const float*)d_in[2];
    const float* wout = (const float*)d_in[3];
    const float* lsc  = (const float*)d_in[4];

    char* ws = (char*)d_ws;
    u16* xb   = (u16*)(ws + 0);           // 16 MB  (dead after qkv_gemm; aliased by AO)
    u16* wqh  = (u16*)(ws + 16777216);    // 6 MB
    u16* wql  = (u16*)(ws + 23068672);    // 6 MB
    u16* wob  = (u16*)(ws + 29360128);    // 2 MB
    u16* qn   = (u16*)(ws + 31457280);    // 16 MB [B,H,N,DH]
    u16* kn   = (u16*)(ws + 48234496);    // 16 MB
    u16* vt   = (u16*)(ws + 65011712);    // 16 MB [B,H,DH,N]
    u16* ao   = xb;                       // alias: [8192,1024] bf16

    prep<<<(XE + WE + OE) / 1024, 256, 0, stream>>>(x, wqkv, wout, xb, wqh, wql, wob);

    qkv_gemm<<<dim3(MROWS / 128, NQKV / 128), 256, 0, stream>>>(xb, wqh, wql, bqkv, qn, kn, vt);
    flash_attn<<<dim3(BATCH * HEADS, NSEQ / 128), 512, 0, stream>>>(qn, kn, vt, lsc, ao);
    out_gemm<<<dim3(MROWS / 128, DMODEL / 128), 256, 0, stream>>>(ao, wob, (float*)d_out);
}

// Round 8
// 354.172 us; speedup vs baseline: 1.1750x; 1.0125x over previous
//
#include <hip/hip_runtime.h>

// ---------- types ----------
typedef __attribute__((ext_vector_type(8))) __bf16 bf16x8;
typedef __attribute__((ext_vector_type(4))) float f32x4;
typedef unsigned short u16;

__device__ __forceinline__ u16 f2bf(float f) {
    union { float f; unsigned u; } v; v.f = f;
    unsigned r = v.u + 0x7FFFu + ((v.u >> 16) & 1u);
    return (u16)(r >> 16);
}
__device__ __forceinline__ float bf2f(u16 h) {
    union { unsigned u; float f; } v; v.u = ((unsigned)h) << 16;
    return v.f;
}
// native cast: single v_cvt op (RNE)
__device__ __forceinline__ u16 f2bf_n(float f) {
    union { __bf16 b; u16 u; } t; t.b = (__bf16)f; return t.u;
}
__device__ __forceinline__ bf16x8 ld_bf16x8(const u16* p) {
    union { uint4 u; bf16x8 b; } t;
    t.u = *(const uint4*)p;
    return t.b;
}
__device__ __forceinline__ void async16(const void* g, const void* l) {
    __builtin_amdgcn_global_load_lds((const __attribute__((address_space(1))) void*)g,
                                     (__attribute__((address_space(3))) void*)l, 16, 0, 0);
}

// ---------- problem constants ----------
#define BATCH 4
#define NSEQ 2048
#define HEADS 16
#define DH 64
#define DMODEL 1024
#define MROWS 8192   // B*N
#define NQKV 3072
#define XE 8388608   // MROWS*DMODEL
#define WE 3145728   // NQKV*DMODEL
#define OE 1048576   // DMODEL*DMODEL

// ---------- fused elementwise prep (R15: 3 launches -> 1) ----------
__global__ __launch_bounds__(256) void prep(
    const float* __restrict__ x, const float* __restrict__ wqkv,
    const float* __restrict__ wout,
    u16* __restrict__ xb, u16* __restrict__ wqh, u16* __restrict__ wql,
    u16* __restrict__ wob) {
    const int i4 = (blockIdx.x * 256 + threadIdx.x) * 4;
    if (i4 < XE) {
        float4 v = *(const float4*)(x + i4);
        ushort4 t = { f2bf(v.x), f2bf(v.y), f2bf(v.z), f2bf(v.w) };
        *(ushort4*)(xb + i4) = t;
    } else if (i4 < XE + WE) {
        const int j = i4 - XE;
        float4 v = *(const float4*)(wqkv + j);
        ushort4 h = { f2bf(v.x), f2bf(v.y), f2bf(v.z), f2bf(v.w) };
        ushort4 l = { f2bf(v.x - bf2f(h.x)), f2bf(v.y - bf2f(h.y)),
                      f2bf(v.z - bf2f(h.z)), f2bf(v.w - bf2f(h.w)) };
        *(ushort4*)(wqh + j) = h;
        *(ushort4*)(wql + j) = l;
    } else {
        const int j = i4 - XE - WE;
        float4 v = *(const float4*)(wout + j);
        ushort4 t = { f2bf(v.x), f2bf(v.y), f2bf(v.z), f2bf(v.w) };
        *(ushort4*)(wob + j) = t;
    }
}

// ---------- fused QKV GEMM + l2-normalize + V-transpose ----------
// R7/R10 winner, unchanged (m97-class ceiling for this shape; R11-R14
// structural escapes all regressed — accepted per methodology rule 10).
__global__ __launch_bounds__(256) void qkv_gemm(
    const u16* __restrict__ A,
    const u16* __restrict__ Bh, const u16* __restrict__ Bl,
    const float* __restrict__ bias,
    u16* __restrict__ Qn, u16* __restrict__ Kn, u16* __restrict__ Vt) {
    const int K = DMODEL, TK = 32;
    __shared__ __align__(16) u16 sA[128 * 32];
    __shared__ __align__(16) u16 sBh[128 * 32], sBl[128 * 32];
    const int tid = threadIdx.x, wave = tid >> 6, lane = tid & 63;
    const int quad = lane >> 4, l16 = lane & 15;
    const int m0 = blockIdx.x * 128, n0 = blockIdx.y * 128;
    const int wm = (wave & 1) * 64, wn = (wave >> 1) * 64;
    f32x4 acc[4][4] = {};

    for (int k0 = 0; k0 < K; k0 += TK) {
        __syncthreads();
        #pragma unroll
        for (int pass = 0; pass < 2; ++pass) {
            const int c = pass * 256 + tid;
            const int row = c >> 2, part = c & 3;
            const int ldsOff = (pass * 256 + wave * 64) * 16;  // bytes; dest = base + lane*16
            const size_t ga = (size_t)(m0 + row) * K + k0 + part * 8;
            const size_t gb = (size_t)(n0 + row) * K + k0 + part * 8;
            async16(A + ga, (const char*)sA + ldsOff);
            async16(Bh + gb, (const char*)sBh + ldsOff);
            async16(Bl + gb, (const char*)sBl + ldsOff);
        }
        __syncthreads();
        bf16x8 a[4];
        #pragma unroll
        for (int mt = 0; mt < 4; ++mt)
            a[mt] = ld_bf16x8(&sA[(wm + mt * 16 + l16) * TK + quad * 8]);
        #pragma unroll
        for (int nt = 0; nt < 4; ++nt) {
            const int cix = wn + nt * 16 + l16;
            bf16x8 bh = ld_bf16x8(&sBh[cix * TK + quad * 8]);
            bf16x8 bl = ld_bf16x8(&sBl[cix * TK + quad * 8]);
            #pragma unroll
            for (int mt = 0; mt < 4; ++mt) {
                acc[mt][nt] = __builtin_amdgcn_mfma_f32_16x16x32_bf16(a[mt], bh, acc[mt][nt], 0, 0, 0);
                acc[mt][nt] = __builtin_amdgcn_mfma_f32_16x16x32_bf16(a[mt], bl, acc[mt][nt], 0, 0, 0);
            }
        }
    }

    #pragma unroll
    for (int nt = 0; nt < 4; ++nt) {
        const float bv = bias[n0 + wn + nt * 16 + l16];
        #pragma unroll
        for (int mt = 0; mt < 4; ++mt)
            #pragma unroll
            for (int r = 0; r < 4; ++r)
                acc[mt][nt][r] += bv;
    }

    if (n0 < 2048) {
        u16* dst = (n0 < 1024) ? Qn : Kn;
        const int nq = (n0 & 1023) + wn;
        const int hh = nq >> 6;
        #pragma unroll
        for (int mt = 0; mt < 4; ++mt) {
            float ss[4] = {};
            #pragma unroll
            for (int nt = 0; nt < 4; ++nt)
                #pragma unroll
                for (int r = 0; r < 4; ++r)
                    ss[r] += acc[mt][nt][r] * acc[mt][nt][r];
            #pragma unroll
            for (int r = 0; r < 4; ++r) {
                ss[r] += __shfl_xor(ss[r], 1);
                ss[r] += __shfl_xor(ss[r], 2);
                ss[r] += __shfl_xor(ss[r], 4);
                ss[r] += __shfl_xor(ss[r], 8);
                ss[r] = 1.f / fmaxf(sqrtf(ss[r]), 1e-12f);
            }
            const int mbase = m0 + wm + mt * 16 + quad * 4;
            const int b = mbase >> 11, n = mbase & 2047;
            #pragma unroll
            for (int r = 0; r < 4; ++r) {
                size_t rowoff = (((size_t)(b * HEADS + hh)) * NSEQ + n + r) * DH;
                #pragma unroll
                for (int nt = 0; nt < 4; ++nt)
                    dst[rowoff + nt * 16 + l16] = f2bf_n(acc[mt][nt][r] * ss[r]);
            }
        }
    } else {
        const int nv = (n0 - 2048) + wn;
        const int hh = nv >> 6;
        #pragma unroll
        for (int nt = 0; nt < 4; ++nt) {
            const int d = nt * 16 + l16;
            #pragma unroll
            for (int mt = 0; mt < 4; ++mt) {
                const int mbase = m0 + wm + mt * 16 + quad * 4;
                const int b = mbase >> 11, n = mbase & 2047;
                ushort4 t;
                t.x = f2bf_n(acc[mt][nt][0]);
                t.y = f2bf_n(acc[mt][nt][1]);
                t.z = f2bf_n(acc[mt][nt][2]);
                t.w = f2bf_n(acc[mt][nt][3]);
                *(ushort4*)&Vt[(((size_t)(b * HEADS + hh)) * DH + d) * NSEQ + n] = t;
            }
        }
    }
}

// ---------- out-proj GEMM: C[m,n] = sum_k A[m,k]*B[n,k], fp32 out ----------
__global__ __launch_bounds__(256) void out_gemm(
    const u16* __restrict__ A, const u16* __restrict__ B, float* __restrict__ C) {
    const int K = DMODEL, N = DMODEL, TK = 32;
    __shared__ __align__(16) u16 sA[128 * 32], sB[128 * 32];
    const int tid = threadIdx.x, wave = tid >> 6, lane = tid & 63;
    const int quad = lane >> 4, l16 = lane & 15;
    const int m0 = blockIdx.x * 128, n0 = blockIdx.y * 128;
    const int wm = (wave & 1) * 64, wn = (wave >> 1) * 64;
    f32x4 acc[4][4] = {};

    for (int k0 = 0; k0 < K; k0 += TK) {
        __syncthreads();
        #pragma unroll
        for (int pass = 0; pass < 2; ++pass) {
            const int c = pass * 256 + tid;
            const int row = c >> 2, part = c & 3;
            const int ldsOff = (pass * 256 + wave * 64) * 16;
            const size_t ga = (size_t)(m0 + row) * K + k0 + part * 8;
            const size_t gb = (size_t)(n0 + row) * K + k0 + part * 8;
            async16(A + ga, (const char*)sA + ldsOff);
            async16(B + gb, (const char*)sB + ldsOff);
        }
        __syncthreads();
        bf16x8 a[4];
        #pragma unroll
        for (int mt = 0; mt < 4; ++mt)
            a[mt] = ld_bf16x8(&sA[(wm + mt * 16 + l16) * TK + quad * 8]);
        #pragma unroll
        for (int nt = 0; nt < 4; ++nt) {
            bf16x8 b = ld_bf16x8(&sB[(wn + nt * 16 + l16) * TK + quad * 8]);
            #pragma unroll
            for (int mt = 0; mt < 4; ++mt)
                acc[mt][nt] = __builtin_amdgcn_mfma_f32_16x16x32_bf16(a[mt], b, acc[mt][nt], 0, 0, 0);
        }
    }
    #pragma unroll
    for (int nt = 0; nt < 4; ++nt) {
        const int n = n0 + wn + nt * 16 + l16;
        #pragma unroll
        for (int mt = 0; mt < 4; ++mt) {
            const int mbase = m0 + wm + mt * 16 + quad * 4;
            #pragma unroll
            for (int r = 0; r < 4; ++r)
                C[(size_t)(mbase + r) * N + n] = acc[mt][nt][r];
        }
    }
}

// ---------- flash attention, cosine specialization, 8-wave blocks ----------
// R16: KVBLK=128. With T12 (R15) the compute phase is pure reg/LDS work, so
// the 4 barriers + 2 lgkmcnt drains per 128 keys are a larger fraction of
// the serial cost. Stage K[128x64] + V[64x128] in one shot (36KB LDS; still
// 4 blocks/CU x 8 waves = 32 waves/CU), then run the two 64-key computes
// back-to-back with NO intervening barrier: barrier pairs 32 -> 16. T14
// reg-prefetch kept: 8 uint4 ping-pong (4/tile), counted vmcnt(4), never
// drained to 0 in the loop. T12 in-register softmax unchanged.
__global__ __launch_bounds__(512) void flash_attn(
    const u16* __restrict__ Q, const u16* __restrict__ Kn, const u16* __restrict__ Vt,
    const float* __restrict__ lsc, u16* __restrict__ AO) {
    const int bh = blockIdx.x;
    const int q0 = blockIdx.y * 128;
    const int h = bh & (HEADS - 1), b = bh >> 4;
    const int tid = threadIdx.x, wave = tid >> 6, lane = tid & 63;
    const int quad = lane >> 4, l16 = lane & 15;
    const float scale = __expf(fminf(lsc[h], 4.6051702f));  // ln(100); here = 10
    const float c1 = scale * 1.4426950408889634f;           // scale*log2(e)

    __shared__ __align__(16) u16 Ks[128][72];     // [key][d]
    __shared__ __align__(16) u16 Vs[64][136];     // [d][key]

    const u16* qbase = Q + ((size_t)bh * NSEQ + q0 + wave * 16) * DH;
    bf16x8 qa[2];
    qa[0] = ld_bf16x8(qbase + l16 * DH + quad * 8);
    qa[1] = ld_bf16x8(qbase + l16 * DH + 32 + quad * 8);

    f32x4 O[4] = {};
    float lrs = 0.f;

    // K staging: rows kr, kr+64 (part kp of 8); V staging: d rows vd, vd+32
    // (part vp of 16) — 4 x 16B per thread per 128-key tile.
    const int kr = tid >> 3, kp = tid & 7;
    const int vd = tid >> 4, vp = tid & 15;
    const u16* kb = Kn + (size_t)bh * NSEQ * DH;
    const u16* vb = Vt + (size_t)bh * DH * NSEQ;

    // prologue: issue tile-0 loads (stay in flight until first ds_write)
    uint4 kA0 = *(const uint4*)(kb + (size_t)kr * DH + kp * 8);
    uint4 kA1 = *(const uint4*)(kb + (size_t)(kr + 64) * DH + kp * 8);
    uint4 vA0 = *(const uint4*)(vb + (size_t)vd * NSEQ + vp * 8);
    uint4 vA1 = *(const uint4*)(vb + (size_t)(vd + 32) * NSEQ + vp * 8);
    uint4 kB0, kB1, vB0, vB1;

    auto compute = [&](int ch) {
        f32x4 S[4] = {};
        __builtin_amdgcn_s_setprio(1);
        #pragma unroll
        for (int nt = 0; nt < 4; ++nt) {
            bf16x8 k0 = ld_bf16x8(&Ks[ch * 64 + nt * 16 + l16][quad * 8]);
            bf16x8 k1 = ld_bf16x8(&Ks[ch * 64 + nt * 16 + l16][32 + quad * 8]);
            S[nt] = __builtin_amdgcn_mfma_f32_16x16x32_bf16(k0, qa[0], S[nt], 0, 0, 0);
            S[nt] = __builtin_amdgcn_mfma_f32_16x16x32_bf16(k1, qa[1], S[nt], 0, 0, 0);
        }
        __builtin_amdgcn_s_setprio(0);

        unsigned w[4][2];
        #pragma unroll
        for (int nt = 0; nt < 4; ++nt) {
            #pragma unroll
            for (int p = 0; p < 2; ++p) {
                float a = __builtin_amdgcn_exp2f(__builtin_fmaf(S[nt][2 * p], c1, -c1));
                float c = __builtin_amdgcn_exp2f(__builtin_fmaf(S[nt][2 * p + 1], c1, -c1));
                lrs += a + c;
                asm("v_cvt_pk_bf16_f32 %0, %1, %2" : "=v"(w[nt][p]) : "v"(a), "v"(c));
            }
        }
        // redistribute to PV A-fragments (all in-register)
        bf16x8 pf[2];
        #pragma unroll
        for (int kc = 0; kc < 2; ++kc) {
            union { unsigned u[4]; bf16x8 b; } t;
            #pragma unroll
            for (int j = 0; j < 4; ++j) {
                const int src = l16 + (2 * (quad & 1) + (j >> 1)) * 16;
                unsigned lo = (unsigned)__shfl((int)w[2 * kc][j & 1], src);
                unsigned hi = (unsigned)__shfl((int)w[2 * kc + 1][j & 1], src);
                t.u[j] = (quad & 2) ? hi : lo;
            }
            pf[kc] = t.b;
        }

        __builtin_amdgcn_s_setprio(1);
        #pragma unroll
        for (int dt = 0; dt < 4; ++dt) {
            bf16x8 v0 = ld_bf16x8(&Vs[dt * 16 + l16][ch * 64 + quad * 8]);
            bf16x8 v1 = ld_bf16x8(&Vs[dt * 16 + l16][ch * 64 + 32 + quad * 8]);
            O[dt] = __builtin_amdgcn_mfma_f32_16x16x32_bf16(pf[0], v0, O[dt], 0, 0, 0);
            O[dt] = __builtin_amdgcn_mfma_f32_16x16x32_bf16(pf[1], v1, O[dt], 0, 0, 0);
        }
        __builtin_amdgcn_s_setprio(0);
    };

    #pragma unroll 1
    for (int kt = 0; kt < NSEQ; kt += 256) {
        // ---- half A: stage tile kt (regs A), prefetch kt+128 -> regs B ----
        asm volatile("s_waitcnt lgkmcnt(0)" ::: "memory");
        __builtin_amdgcn_s_barrier();                    // all waves done reading LDS
        {
            const int nk = kt + 128;
            kB0 = *(const uint4*)(kb + (size_t)(nk + kr) * DH + kp * 8);
            kB1 = *(const uint4*)(kb + (size_t)(nk + kr + 64) * DH + kp * 8);
            vB0 = *(const uint4*)(vb + (size_t)vd * NSEQ + nk + vp * 8);
            vB1 = *(const uint4*)(vb + (size_t)(vd + 32) * NSEQ + nk + vp * 8);
        }
        asm volatile("s_waitcnt vmcnt(4)" ::: "memory"); // tile-kt regs landed; 4 newer in flight
        *(uint4*)&Ks[kr][kp * 8] = kA0;
        *(uint4*)&Ks[kr + 64][kp * 8] = kA1;
        *(uint4*)&Vs[vd][vp * 8] = vA0;
        *(uint4*)&Vs[vd + 32][vp * 8] = vA1;
        asm volatile("s_waitcnt lgkmcnt(0)" ::: "memory");
        __builtin_amdgcn_s_barrier();                    // staging visible to all
        compute(0); compute(1);

        // ---- half B: stage tile kt+128 (regs B), prefetch kt+256 -> regs A ----
        asm volatile("s_waitcnt lgkmcnt(0)" ::: "memory");
        __builtin_amdgcn_s_barrier();
        {
            // last iteration: no tile kt+256 exists; re-read tile 0 (valid
            // memory, result unused) to keep the pipeline shape uniform.
            const int nk = (kt + 256) < NSEQ ? (kt + 256) : 0;
            kA0 = *(const uint4*)(kb + (size_t)(nk + kr) * DH + kp * 8);
            kA1 = *(const uint4*)(kb + (size_t)(nk + kr + 64) * DH + kp * 8);
            vA0 = *(const uint4*)(vb + (size_t)vd * NSEQ + nk + vp * 8);
            vA1 = *(const uint4*)(vb + (size_t)(vd + 32) * NSEQ + nk + vp * 8);
        }
        asm volatile("s_waitcnt vmcnt(4)" ::: "memory");
        *(uint4*)&Ks[kr][kp * 8] = kB0;
        *(uint4*)&Ks[kr + 64][kp * 8] = kB1;
        *(uint4*)&Vs[vd][vp * 8] = vB0;
        *(uint4*)&Vs[vd + 32][vp * 8] = vB1;
        asm volatile("s_waitcnt lgkmcnt(0)" ::: "memory");
        __builtin_amdgcn_s_barrier();
        compute(0); compute(1);
    }

    // denominator: sum over quads (each lane has partial for q=l16)
    lrs += __shfl_xor(lrs, 16);
    lrs += __shfl_xor(lrs, 32);

    #pragma unroll
    for (int r = 0; r < 4; ++r) {
        const float lq = __shfl(lrs, quad * 4 + r);      // total for q=quad*4+r
        const float inv = 1.f / fmaxf(lq, 1e-30f);
        size_t orow = (size_t)b * NSEQ + q0 + wave * 16 + quad * 4 + r;
        #pragma unroll
        for (int dt = 0; dt < 4; ++dt)
            AO[orow * DMODEL + h * DH + dt * 16 + l16] = f2bf_n(O[dt][r] * inv);
    }
}

// ---------- launch ----------
extern "C" void kernel_launch(void* const* d_in, const int* in_sizes, int n_in,
                              void* d_out, int out_size, void* d_ws, size_t ws_size,
                              hipStream_t stream) {
    const float* x    = (const float*)d_in[0];
    const float* wqkv = (const float*)d_in[1];
    const float* bqkv = (const float*)d_in[2];
    const float* wout = (const float*)d_in[3];
    const float* lsc  = (const float*)d_in[4];

    char* ws = (char*)d_ws;
    u16* xb   = (u16*)(ws + 0);           // 16 MB  (dead after qkv_gemm; aliased by AO)
    u16* wqh  = (u16*)(ws + 16777216);    // 6 MB
    u16* wql  = (u16*)(ws + 23068672);    // 6 MB
    u16* wob  = (u16*)(ws + 29360128);    // 2 MB
    u16* qn   = (u16*)(ws + 31457280);    // 16 MB [B,H,N,DH]
    u16* kn   = (u16*)(ws + 48234496);    // 16 MB
    u16* vt   = (u16*)(ws + 65011712);    // 16 MB [B,H,DH,N]
    u16* ao   = xb;                       // alias: [8192,1024] bf16

    prep<<<(XE + WE + OE) / 1024, 256, 0, stream>>>(x, wqkv, wout, xb, wqh, wql, wob);

    qkv_gemm<<<dim3(MROWS / 128, NQKV / 128), 256, 0, stream>>>(xb, wqh, wql, bqkv, qn, kn, vt);
    flash_attn<<<dim3(BATCH * HEADS, NSEQ / 128), 512, 0, stream>>>(qn, kn, vt, lsc, ao);
    out_gemm<<<dim3(MROWS / 128, DMODEL / 128), 256, 0, stream>>>(ao, wob, (float*)d_out);
}